// Round 1
// 1597.198 us; speedup vs baseline: 1.2551x; 1.2551x over previous
//
#include <hip/hip_runtime.h>
#include <stdint.h>

#define B_DIM 8
#define S_DIM 4096
#define F_DIM 512
#define H_DIM 2048
#define W_DIM 16
#define L_DIM 4081               // S - W + 1
#define M_TOT 32648              // B * L
#define K1_DIM 8192              // W * F
#define SXF 2097152              // S * F

typedef __bf16 bf16x8 __attribute__((ext_vector_type(8)));
typedef float f32x4 __attribute__((ext_vector_type(4)));

__device__ __forceinline__ unsigned short f2bf(float f) {
  union { float f; uint32_t u; } a; a.f = f;
  return (unsigned short)((a.u + 0x7fffu + ((a.u >> 16) & 1u)) >> 16);
}

__device__ __forceinline__ void async16(const void* g, void* l) {
  __builtin_amdgcn_global_load_lds(
      (__attribute__((address_space(1))) void*)(uintptr_t)g,
      (__attribute__((address_space(3))) void*)l, 16, 0, 0);
}

#define SBAR   __builtin_amdgcn_s_barrier()
#define SCHED0 __builtin_amdgcn_sched_barrier(0)
#define PRIO1  __builtin_amdgcn_s_setprio(1)
#define PRIO0  __builtin_amdgcn_s_setprio(0)
#define LGKM0  asm volatile("s_waitcnt lgkmcnt(0)" ::: "memory")
#define VM10   asm volatile("s_waitcnt vmcnt(10)" ::: "memory")
#define VM0    asm volatile("s_waitcnt vmcnt(0)"  ::: "memory")

// 16 MFMAs: acc[MO..MO+3][0..3] += a0..a3 x bb0..bb3
#define MFMA16(MO) \
  acc[(MO)+0][0] = __builtin_amdgcn_mfma_f32_16x16x32_bf16(a0, bb0, acc[(MO)+0][0], 0, 0, 0); \
  acc[(MO)+0][1] = __builtin_amdgcn_mfma_f32_16x16x32_bf16(a0, bb1, acc[(MO)+0][1], 0, 0, 0); \
  acc[(MO)+0][2] = __builtin_amdgcn_mfma_f32_16x16x32_bf16(a0, bb2, acc[(MO)+0][2], 0, 0, 0); \
  acc[(MO)+0][3] = __builtin_amdgcn_mfma_f32_16x16x32_bf16(a0, bb3, acc[(MO)+0][3], 0, 0, 0); \
  acc[(MO)+1][0] = __builtin_amdgcn_mfma_f32_16x16x32_bf16(a1, bb0, acc[(MO)+1][0], 0, 0, 0); \
  acc[(MO)+1][1] = __builtin_amdgcn_mfma_f32_16x16x32_bf16(a1, bb1, acc[(MO)+1][1], 0, 0, 0); \
  acc[(MO)+1][2] = __builtin_amdgcn_mfma_f32_16x16x32_bf16(a1, bb2, acc[(MO)+1][2], 0, 0, 0); \
  acc[(MO)+1][3] = __builtin_amdgcn_mfma_f32_16x16x32_bf16(a1, bb3, acc[(MO)+1][3], 0, 0, 0); \
  acc[(MO)+2][0] = __builtin_amdgcn_mfma_f32_16x16x32_bf16(a2, bb0, acc[(MO)+2][0], 0, 0, 0); \
  acc[(MO)+2][1] = __builtin_amdgcn_mfma_f32_16x16x32_bf16(a2, bb1, acc[(MO)+2][1], 0, 0, 0); \
  acc[(MO)+2][2] = __builtin_amdgcn_mfma_f32_16x16x32_bf16(a2, bb2, acc[(MO)+2][2], 0, 0, 0); \
  acc[(MO)+2][3] = __builtin_amdgcn_mfma_f32_16x16x32_bf16(a2, bb3, acc[(MO)+2][3], 0, 0, 0); \
  acc[(MO)+3][0] = __builtin_amdgcn_mfma_f32_16x16x32_bf16(a3, bb0, acc[(MO)+3][0], 0, 0, 0); \
  acc[(MO)+3][1] = __builtin_amdgcn_mfma_f32_16x16x32_bf16(a3, bb1, acc[(MO)+3][1], 0, 0, 0); \
  acc[(MO)+3][2] = __builtin_amdgcn_mfma_f32_16x16x32_bf16(a3, bb2, acc[(MO)+3][2], 0, 0, 0); \
  acc[(MO)+3][3] = __builtin_amdgcn_mfma_f32_16x16x32_bf16(a3, bb3, acc[(MO)+3][3], 0, 0, 0);

// ---------------- GEMM1: h = relu(x_hankel @ w1 + b1) ----------------------
// 8-phase (T3+T4+T5) 256x256 tile, BK=64, 8 waves (2M x 4N, 128x64 each).
// LDS 128 KB = 2 dbuf x (A 32KB + B 32KB); each K-tile = 4 halves of 16KB
// (A-ks0, A-ks1, B-ks0, B-ks1), staged 2 x async16/thread per half.
// Fragment-order chunk layout (conflict-free, verified 0 bank conflicts):
// chunk c = T*64 + g*16 + m16; consumer lane reads chunk T*64 + lane.
// Phase q of tile T: {ds_read subtile; issue 1 half for tile T+1/T+2;
//  s_barrier; lgkmcnt(0); setprio(1); 16 MFMA; setprio(0);
//  [vmcnt(10) at q1/q3]; s_barrier}.  Counted vmcnt = 5 halves in flight;
// each half is issued 5-7 phases before its first ds_read. Last 2 tiles
// use vmcnt(0) (issue guards shrink the in-flight set; counted wait would
// no longer imply landing).
__global__ __launch_bounds__(512, 2) void gemm1_kernel(
    const unsigned short* __restrict__ xb,
    const unsigned short* __restrict__ w1t,
    const float* __restrict__ bias1,
    unsigned short* __restrict__ h)
{
  __shared__ alignas(16) unsigned short lsA[32768];  // 2 buf x 2 ks x 16KB
  __shared__ alignas(16) unsigned short lsB[32768];

  const int tid  = threadIdx.x;
  const int lane = tid & 63;
  const int wave = tid >> 6;           // 0..7
  const int id = blockIdx.x;
  const int nt = id & 7;               // XCD-pinned B column
  const int mt = id >> 3;

  // staging decode: chunk c0 = tid (m16=c&15, g=(c>>4)&3, T=c>>6), c1 = tid+512
  const int m16 = tid & 15;
  const int g   = (tid >> 4) & 3;
  const int T0  = tid >> 6;            // 0..7 ; c1 has T0+8

  int rowA0 = mt * 256 + T0 * 16 + m16;
  int rowA1 = rowA0 + 128;
  if (rowA0 >= M_TOT) rowA0 = M_TOT - 1;
  if (rowA1 >= M_TOT) rowA1 = M_TOT - 1;
  const int b0 = rowA0 / L_DIM, l0 = rowA0 - b0 * L_DIM;
  const int b1 = rowA1 / L_DIM, l1 = rowA1 - b1 * L_DIM;
  // Hankel row m is 8192 CONTIGUOUS elements starting at x[b][l][0]
  const unsigned short* pA0 = xb + (size_t)b0 * SXF + (size_t)l0 * F_DIM + g * 8;
  const unsigned short* pA1 = xb + (size_t)b1 * SXF + (size_t)l1 * F_DIM + g * 8;

  const int colB0 = nt * 256 + T0 * 16 + m16;
  const unsigned short* pB0 = w1t + (size_t)colB0 * K1_DIM + g * 8;
  const unsigned short* pB1 = pB0 + (size_t)128 * K1_DIM;

  const int wm = wave >> 2;            // 0..1 : 128-row band
  const int wn = wave & 3;             // 0..3 : 64-col band
  const int aBase = wm * 512 + lane;   // chunk index of A frag (T=wm*8..)
  const int bBase = wn * 256 + lane;   // chunk index of B frag (Tn=wn*4..)

  f32x4 acc[8][4] = {};

  const int KT = K1_DIM / 64;          // 128 K-tiles

#define STAGE_A(TT, ks) { \
    unsigned short* d_ = lsA + ((TT) & 1) * 16384 + (ks) * 8192 + tid * 8; \
    const int ko_ = (TT) * 64 + (ks) * 32; \
    async16(pA0 + ko_, d_); async16(pA1 + ko_, d_ + 4096); }
#define STAGE_B(TT, ks) { \
    unsigned short* d_ = lsB + ((TT) & 1) * 16384 + (ks) * 8192 + tid * 8; \
    const int ko_ = (TT) * 64 + (ks) * 32; \
    async16(pB0 + ko_, d_); async16(pB1 + ko_, d_ + 4096); }

  // prologue: 7 halves (14 loads); need oldest 4 landed -> vmcnt(10)
  STAGE_B(0, 0); STAGE_A(0, 0); STAGE_B(0, 1); STAGE_A(0, 1);
  STAGE_B(1, 0); STAGE_A(1, 0); STAGE_B(1, 1);
  VM10; SBAR;

  for (int kt = 0; kt < KT; ++kt) {
    const bf16x8* lA = (const bf16x8*)(lsA + (kt & 1) * 16384);
    const bf16x8* lB = (const bf16x8*)(lsB + (kt & 1) * 16384);
    const bool wlast = (kt >= KT - 2);
    bf16x8 a0, a1, a2, a3, bb0, bb1, bb2, bb3;

    // q0: mh=0 ks=0 ; stage A-ks1(kt+1)
    a0 = lA[aBase];       a1 = lA[aBase + 64];
    a2 = lA[aBase + 128]; a3 = lA[aBase + 192];
    bb0 = lB[bBase];       bb1 = lB[bBase + 64];
    bb2 = lB[bBase + 128]; bb3 = lB[bBase + 192];
    if (kt + 1 < KT) STAGE_A(kt + 1, 1);
    SBAR; LGKM0; SCHED0; PRIO1;
    MFMA16(0);
    PRIO0; SBAR;

    // q1: mh=1 ks=0 ; stage B-ks0(kt+2) ; counted wait
    a0 = lA[aBase + 256]; a1 = lA[aBase + 320];
    a2 = lA[aBase + 384]; a3 = lA[aBase + 448];
    if (kt + 2 < KT) STAGE_B(kt + 2, 0);
    SBAR; LGKM0; SCHED0; PRIO1;
    MFMA16(4);
    PRIO0;
    if (wlast) { VM0; } else { VM10; }
    SBAR;

    // q2: mh=0 ks=1 ; stage A-ks0(kt+2)
    a0 = lA[1024 + aBase];       a1 = lA[1024 + aBase + 64];
    a2 = lA[1024 + aBase + 128]; a3 = lA[1024 + aBase + 192];
    bb0 = lB[1024 + bBase];       bb1 = lB[1024 + bBase + 64];
    bb2 = lB[1024 + bBase + 128]; bb3 = lB[1024 + bBase + 192];
    if (kt + 2 < KT) STAGE_A(kt + 2, 0);
    SBAR; LGKM0; SCHED0; PRIO1;
    MFMA16(0);
    PRIO0; SBAR;

    // q3: mh=1 ks=1 ; stage B-ks1(kt+2) ; counted wait
    a0 = lA[1024 + aBase + 256]; a1 = lA[1024 + aBase + 320];
    a2 = lA[1024 + aBase + 384]; a3 = lA[1024 + aBase + 448];
    if (kt + 2 < KT) STAGE_B(kt + 2, 1);
    SBAR; LGKM0; SCHED0; PRIO1;
    MFMA16(4);
    PRIO0;
    if (wlast) { VM0; } else { VM10; }
    SBAR;
  }
#undef STAGE_A
#undef STAGE_B

  // C/D layout: col = lane&15, row = (lane>>4)*4 + reg
  const int ncol = nt * 256 + wn * 64 + (lane & 15);
  const int mrow = mt * 256 + wm * 128 + (lane >> 4) * 4;
#pragma unroll
  for (int u = 0; u < 4; ++u) {
    const int n = ncol + u * 16;
    const float bv = bias1[n];
#pragma unroll
    for (int t = 0; t < 8; ++t) {
#pragma unroll
      for (int r = 0; r < 4; ++r) {
        const int m = mrow + t * 16 + r;
        if (m < M_TOT) {
          float v = acc[t][u][r] + bv;
          v = v > 0.f ? v : 0.f;
          h[(size_t)m * H_DIM + n] = f2bf(v);
        }
      }
    }
  }
}

// ---------------- GEMM2: y = h @ w2 + b2, same 8-phase structure -----------
__global__ __launch_bounds__(512, 2) void gemm2_kernel(
    const unsigned short* __restrict__ hmat,
    const unsigned short* __restrict__ w2t,   // [512][2048]
    const float* __restrict__ bias2,
    float* __restrict__ out)
{
  __shared__ alignas(16) unsigned short lsA[32768];
  __shared__ alignas(16) unsigned short lsB[32768];

  const int tid  = threadIdx.x;
  const int lane = tid & 63;
  const int wave = tid >> 6;
  const int id = blockIdx.x;
  const int nt = id & 1;               // 2 col tiles of 256 (N=512)
  const int mt = id >> 1;

  const int m16 = tid & 15;
  const int g   = (tid >> 4) & 3;
  const int T0  = tid >> 6;

  int rowA0 = mt * 256 + T0 * 16 + m16;
  int rowA1 = rowA0 + 128;
  if (rowA0 >= M_TOT) rowA0 = M_TOT - 1;
  if (rowA1 >= M_TOT) rowA1 = M_TOT - 1;
  const unsigned short* pA0 = hmat + (size_t)rowA0 * H_DIM + g * 8;
  const unsigned short* pA1 = hmat + (size_t)rowA1 * H_DIM + g * 8;

  const int colB0 = nt * 256 + T0 * 16 + m16;
  const unsigned short* pB0 = w2t + (size_t)colB0 * H_DIM + g * 8;
  const unsigned short* pB1 = pB0 + (size_t)128 * H_DIM;

  const int wm = wave >> 2;
  const int wn = wave & 3;
  const int aBase = wm * 512 + lane;
  const int bBase = wn * 256 + lane;

  f32x4 acc[8][4] = {};

  const int KT = H_DIM / 64;           // 32 K-tiles

#define STAGE_A(TT, ks) { \
    unsigned short* d_ = lsA + ((TT) & 1) * 16384 + (ks) * 8192 + tid * 8; \
    const int ko_ = (TT) * 64 + (ks) * 32; \
    async16(pA0 + ko_, d_); async16(pA1 + ko_, d_ + 4096); }
#define STAGE_B(TT, ks) { \
    unsigned short* d_ = lsB + ((TT) & 1) * 16384 + (ks) * 8192 + tid * 8; \
    const int ko_ = (TT) * 64 + (ks) * 32; \
    async16(pB0 + ko_, d_); async16(pB1 + ko_, d_ + 4096); }

  STAGE_B(0, 0); STAGE_A(0, 0); STAGE_B(0, 1); STAGE_A(0, 1);
  STAGE_B(1, 0); STAGE_A(1, 0); STAGE_B(1, 1);
  VM10; SBAR;

  for (int kt = 0; kt < KT; ++kt) {
    const bf16x8* lA = (const bf16x8*)(lsA + (kt & 1) * 16384);
    const bf16x8* lB = (const bf16x8*)(lsB + (kt & 1) * 16384);
    const bool wlast = (kt >= KT - 2);
    bf16x8 a0, a1, a2, a3, bb0, bb1, bb2, bb3;

    // q0
    a0 = lA[aBase];       a1 = lA[aBase + 64];
    a2 = lA[aBase + 128]; a3 = lA[aBase + 192];
    bb0 = lB[bBase];       bb1 = lB[bBase + 64];
    bb2 = lB[bBase + 128]; bb3 = lB[bBase + 192];
    if (kt + 1 < KT) STAGE_A(kt + 1, 1);
    SBAR; LGKM0; SCHED0; PRIO1;
    MFMA16(0);
    PRIO0; SBAR;

    // q1
    a0 = lA[aBase + 256]; a1 = lA[aBase + 320];
    a2 = lA[aBase + 384]; a3 = lA[aBase + 448];
    if (kt + 2 < KT) STAGE_B(kt + 2, 0);
    SBAR; LGKM0; SCHED0; PRIO1;
    MFMA16(4);
    PRIO0;
    if (wlast) { VM0; } else { VM10; }
    SBAR;

    // q2
    a0 = lA[1024 + aBase];       a1 = lA[1024 + aBase + 64];
    a2 = lA[1024 + aBase + 128]; a3 = lA[1024 + aBase + 192];
    bb0 = lB[1024 + bBase];       bb1 = lB[1024 + bBase + 64];
    bb2 = lB[1024 + bBase + 128]; bb3 = lB[1024 + bBase + 192];
    if (kt + 2 < KT) STAGE_A(kt + 2, 0);
    SBAR; LGKM0; SCHED0; PRIO1;
    MFMA16(0);
    PRIO0; SBAR;

    // q3
    a0 = lA[1024 + aBase + 256]; a1 = lA[1024 + aBase + 320];
    a2 = lA[1024 + aBase + 384]; a3 = lA[1024 + aBase + 448];
    if (kt + 2 < KT) STAGE_B(kt + 2, 1);
    SBAR; LGKM0; SCHED0; PRIO1;
    MFMA16(4);
    PRIO0;
    if (wlast) { VM0; } else { VM10; }
    SBAR;
  }
#undef STAGE_A
#undef STAGE_B

  const int ncol = nt * 256 + wn * 64 + (lane & 15);
  const int mrow = mt * 256 + wm * 128 + (lane >> 4) * 4;
#pragma unroll
  for (int u = 0; u < 4; ++u) {
    const int n = ncol + u * 16;
    const float bv = bias2[n];
#pragma unroll
    for (int t = 0; t < 8; ++t) {
#pragma unroll
      for (int r = 0; r < 4; ++r) {
        const int m = mrow + t * 16 + r;
        if (m < M_TOT) {
          const int b = m / L_DIM;
          const int l = m - b * L_DIM;
          out[(size_t)b * SXF + (size_t)l * F_DIM + n] = acc[t][u][r] + bv;
        }
      }
    }
  }
}

// ---------------- conversion / transpose / pad helpers ----------------------
__global__ void cvt_bf16_kernel(const float* __restrict__ in,
                                unsigned short* __restrict__ out, int n4) {
  int idx = blockIdx.x * 256 + threadIdx.x;
  if (idx < n4) {
    float4 v = ((const float4*)in)[idx];
    ushort4 o;
    o.x = f2bf(v.x); o.y = f2bf(v.y); o.z = f2bf(v.z); o.w = f2bf(v.w);
    ((ushort4*)out)[idx] = o;
  }
}

// out[c][r] = bf16(in[r][c]); R, C multiples of 64
__global__ void transpose_cvt_kernel(const float* __restrict__ in,
                                     unsigned short* __restrict__ out, int R, int C) {
  __shared__ unsigned short tile[64][72];
  const int tx = threadIdx.x & 15;
  const int ty = threadIdx.x >> 4;
  const int r0 = blockIdx.x * 64;
  const int c0 = blockIdx.y * 64;
#pragma unroll
  for (int i = 0; i < 4; ++i) {
    const int r = r0 + ty + i * 16;
    float4 v = *(const float4*)(in + (size_t)r * C + c0 + tx * 4);
    tile[ty + i * 16][tx * 4 + 0] = f2bf(v.x);
    tile[ty + i * 16][tx * 4 + 1] = f2bf(v.y);
    tile[ty + i * 16][tx * 4 + 2] = f2bf(v.z);
    tile[ty + i * 16][tx * 4 + 3] = f2bf(v.w);
  }
  __syncthreads();
#pragma unroll
  for (int i = 0; i < 4; ++i) {
    const int c = c0 + ty + i * 16;
    ushort4 o;
    o.x = tile[tx * 4 + 0][ty + i * 16];
    o.y = tile[tx * 4 + 1][ty + i * 16];
    o.z = tile[tx * 4 + 2][ty + i * 16];
    o.w = tile[tx * 4 + 3][ty + i * 16];
    *(ushort4*)(out + (size_t)c * R + r0 + tx * 4) = o;
  }
}

__global__ void zero_pad_kernel(float* __restrict__ out) {
  int idx = blockIdx.x * 256 + threadIdx.x;          // 8 * 15 * 128 float4s
  if (idx < B_DIM * 15 * 128) {
    int b = idx / (15 * 128);
    int rem = idx - b * (15 * 128);
    int l = L_DIM + rem / 128;
    int f4 = rem - (rem / 128) * 128;
    ((float4*)out)[(size_t)b * (SXF / 4) + (size_t)l * 128 + f4] =
        make_float4(0.f, 0.f, 0.f, 0.f);
  }
}

__global__ void fill_sentinel(float* out, int n) {   // distinctive ws-too-small marker
  int idx = blockIdx.x * 256 + threadIdx.x;
  if (idx < n) out[idx] = 12345.0f;
}

extern "C" void kernel_launch(void* const* d_in, const int* in_sizes, int n_in,
                              void* d_out, int out_size, void* d_ws, size_t ws_size,
                              hipStream_t stream) {
  const float* x  = (const float*)d_in[0];
  const float* w1 = (const float*)d_in[1];
  const float* b1 = (const float*)d_in[2];
  const float* w2 = (const float*)d_in[3];
  const float* b2 = (const float*)d_in[4];
  float* out = (float*)d_out;

  const size_t OFF_H   = 0;                               // 32648*2048*2 = 133726208
  const size_t OFF_XB  = 133726208;                       // 16777216*2   = 33554432
  const size_t OFF_W1T = OFF_XB + 33554432;               // 8192*2048*2  = 33554432
  const size_t OFF_W2T = OFF_W1T + 33554432;              // 2048*512*2   = 2097152
  const size_t WS_NEED = OFF_W2T + 2097152;               // ~202.9 MB

  if (ws_size < WS_NEED) {
    fill_sentinel<<<65536, 256, 0, stream>>>(out, out_size);
    return;
  }

  unsigned short* hbuf = (unsigned short*)((char*)d_ws + OFF_H);
  unsigned short* xb   = (unsigned short*)((char*)d_ws + OFF_XB);
  unsigned short* w1t  = (unsigned short*)((char*)d_ws + OFF_W1T);
  unsigned short* w2t  = (unsigned short*)((char*)d_ws + OFF_W2T);

  cvt_bf16_kernel<<<16384, 256, 0, stream>>>(x, xb, 4194304);
  transpose_cvt_kernel<<<dim3(128, 32), 256, 0, stream>>>(w1, w1t, 8192, 2048);
  transpose_cvt_kernel<<<dim3(32, 8), 256, 0, stream>>>(w2, w2t, 2048, 512);
  gemm1_kernel<<<1024, 512, 0, stream>>>(xb, w1t, b1, hbuf);
  gemm2_kernel<<<256, 512, 0, stream>>>(hbuf, w2t, b2, out);
  zero_pad_kernel<<<60, 256, 0, stream>>>(out);
}

// Round 2
// 1578.067 us; speedup vs baseline: 1.2703x; 1.0121x over previous
//
#include <hip/hip_runtime.h>
#include <stdint.h>

#define B_DIM 8
#define S_DIM 4096
#define F_DIM 512
#define H_DIM 2048
#define W_DIM 16
#define L_DIM 4081               // S - W + 1
#define M_TOT 32648              // B * L
#define K1_DIM 8192              // W * F
#define SXF 2097152              // S * F

typedef __bf16 bf16x8 __attribute__((ext_vector_type(8)));
typedef float f32x4 __attribute__((ext_vector_type(4)));

__device__ __forceinline__ unsigned short f2bf(float f) {
  union { float f; uint32_t u; } a; a.f = f;
  return (unsigned short)((a.u + 0x7fffu + ((a.u >> 16) & 1u)) >> 16);
}

__device__ __forceinline__ void async16(const void* g, void* l) {
  __builtin_amdgcn_global_load_lds(
      (__attribute__((address_space(1))) void*)(uintptr_t)g,
      (__attribute__((address_space(3))) void*)l, 16, 0, 0);
}

#define SBAR   __builtin_amdgcn_s_barrier()
#define SCHED0 __builtin_amdgcn_sched_barrier(0)
#define PRIO1  __builtin_amdgcn_s_setprio(1)
#define PRIO0  __builtin_amdgcn_s_setprio(0)
#define VM4    asm volatile("s_waitcnt vmcnt(4)" ::: "memory")
#define VM0    asm volatile("s_waitcnt vmcnt(0)" ::: "memory")

// one accumulator row: acc[T][0..3] += AR x b0..b3
#define MROW(T, AR) \
  acc[T][0] = __builtin_amdgcn_mfma_f32_16x16x32_bf16(AR, b0, acc[T][0], 0, 0, 0); \
  acc[T][1] = __builtin_amdgcn_mfma_f32_16x16x32_bf16(AR, b1, acc[T][1], 0, 0, 0); \
  acc[T][2] = __builtin_amdgcn_mfma_f32_16x16x32_bf16(AR, b2, acc[T][2], 0, 0, 0); \
  acc[T][3] = __builtin_amdgcn_mfma_f32_16x16x32_bf16(AR, b3, acc[T][3], 0, 0, 0);

#define MFMA32 \
  MROW(0, a0) MROW(1, a1) MROW(2, a2) MROW(3, a3) \
  MROW(4, a4) MROW(5, a5) MROW(6, a6) MROW(7, a7)

#define LOAD_KS(OFS) \
  a0 = lA[(OFS) + aBase];       a1 = lA[(OFS) + aBase + 64]; \
  a2 = lA[(OFS) + aBase + 128]; a3 = lA[(OFS) + aBase + 192]; \
  a4 = lA[(OFS) + aBase + 256]; a5 = lA[(OFS) + aBase + 320]; \
  a6 = lA[(OFS) + aBase + 384]; a7 = lA[(OFS) + aBase + 448]; \
  b0 = lB[(OFS) + bBase];       b1 = lB[(OFS) + bBase + 64]; \
  b2 = lB[(OFS) + bBase + 128]; b3 = lB[(OFS) + bBase + 192];

// ---------------- GEMM1: h = relu(x_hankel @ w1 + b1) ----------------------
// 256x256 tile, BK=64, 8 waves (2M x 4N, each 128x64). 2 sync points per
// K-tile (vs 8 in prior rev, which lockstepped every 16-MFMA phase and
// capped MfmaUtil at 33%):
//   region1: read ks0 frags -> 32 MFMA
//   SBAR (ks0 of cur buf now dead) ; stage ks0(kt+2) into it
//   region2: read ks1 frags -> 32 MFMA
//   vmcnt(4) (forces tile kt+1 fully landed; newest 4 = ks0(kt+2)) ; SBAR
//   (ks1 of cur buf now dead) ; stage ks1(kt+2) into it
// Stages pinned after barriers via sched_barrier(0); ds_reads cannot cross
// the vmcnt asm (memory clobber); compiler inserts its own lgkmcnt waits.
// Counted vmcnt never 0 in steady state (drain only for kt >= KT-2).
__global__ __launch_bounds__(512, 2) void gemm1_kernel(
    const unsigned short* __restrict__ xb,
    const unsigned short* __restrict__ w1t,
    const float* __restrict__ bias1,
    unsigned short* __restrict__ h)
{
  __shared__ alignas(16) unsigned short lsA[32768];  // 2 buf x 2 ks x 16KB
  __shared__ alignas(16) unsigned short lsB[32768];

  const int tid  = threadIdx.x;
  const int lane = tid & 63;
  const int wave = tid >> 6;           // 0..7
  const int id = blockIdx.x;
  const int nt = id & 7;               // XCD-pinned B column
  const int mt = id >> 3;

  // staging decode: chunk c0 = tid (m16=c&15, g=(c>>4)&3, T=c>>6), c1 = tid+512
  const int m16 = tid & 15;
  const int g   = (tid >> 4) & 3;
  const int T0  = tid >> 6;            // 0..7 ; c1 has T0+8

  int rowA0 = mt * 256 + T0 * 16 + m16;
  int rowA1 = rowA0 + 128;
  if (rowA0 >= M_TOT) rowA0 = M_TOT - 1;
  if (rowA1 >= M_TOT) rowA1 = M_TOT - 1;
  const int b0i = rowA0 / L_DIM, l0 = rowA0 - b0i * L_DIM;
  const int b1i = rowA1 / L_DIM, l1 = rowA1 - b1i * L_DIM;
  // Hankel row m is 8192 CONTIGUOUS elements starting at x[b][l][0]
  const unsigned short* pA0 = xb + (size_t)b0i * SXF + (size_t)l0 * F_DIM + g * 8;
  const unsigned short* pA1 = xb + (size_t)b1i * SXF + (size_t)l1 * F_DIM + g * 8;

  const int colB0 = nt * 256 + T0 * 16 + m16;
  const unsigned short* pB0 = w1t + (size_t)colB0 * K1_DIM + g * 8;
  const unsigned short* pB1 = pB0 + (size_t)128 * K1_DIM;

  const int wm = wave >> 2;            // 0..1 : 128-row band
  const int wn = wave & 3;             // 0..3 : 64-col band
  const int aBase = wm * 512 + lane;   // chunk index of A frag
  const int bBase = wn * 256 + lane;   // chunk index of B frag

  f32x4 acc[8][4] = {};

  const int KT = K1_DIM / 64;          // 128 K-tiles

#define STAGE_A(TT, ks) { \
    unsigned short* d_ = lsA + ((TT) & 1) * 16384 + (ks) * 8192 + tid * 8; \
    const int ko_ = (TT) * 64 + (ks) * 32; \
    async16(pA0 + ko_, d_); async16(pA1 + ko_, d_ + 4096); }
#define STAGE_B(TT, ks) { \
    unsigned short* d_ = lsB + ((TT) & 1) * 16384 + (ks) * 8192 + tid * 8; \
    const int ko_ = (TT) * 64 + (ks) * 32; \
    async16(pB0 + ko_, d_); async16(pB1 + ko_, d_ + 4096); }

  // prologue: tile0 (4 halves) + ks0(1); wait newest-4 out = ks0(1)
  STAGE_A(0, 0); STAGE_B(0, 0); STAGE_A(0, 1); STAGE_B(0, 1);
  STAGE_A(1, 0); STAGE_B(1, 0);
  VM4; SBAR; SCHED0;
  STAGE_A(1, 1); STAGE_B(1, 1);

  for (int kt = 0; kt < KT; ++kt) {
    const bf16x8* lA = (const bf16x8*)(lsA + (kt & 1) * 16384);
    const bf16x8* lB = (const bf16x8*)(lsB + (kt & 1) * 16384);
    bf16x8 a0, a1, a2, a3, a4, a5, a6, a7, b0, b1, b2, b3;

    // ---- region 1: ks0 ----
    LOAD_KS(0);
    PRIO1;
    MFMA32;
    PRIO0;
    SBAR; SCHED0;                      // cur-buf ks0 dead
    if (kt + 2 < KT) { STAGE_A(kt + 2, 0); STAGE_B(kt + 2, 0); }

    // ---- region 2: ks1 ----
    LOAD_KS(1024);
    PRIO1;
    MFMA32;
    PRIO0;
    SCHED0;
    if (kt >= KT - 2) { VM0; } else { VM4; }   // tile kt+1 fully landed
    SBAR; SCHED0;                      // cur-buf ks1 dead
    if (kt + 2 < KT) { STAGE_A(kt + 2, 1); STAGE_B(kt + 2, 1); }
  }
#undef STAGE_A
#undef STAGE_B

  // C/D layout: col = lane&15, row = (lane>>4)*4 + reg
  const int ncol = nt * 256 + wn * 64 + (lane & 15);
  const int mrow = mt * 256 + wm * 128 + (lane >> 4) * 4;
#pragma unroll
  for (int u = 0; u < 4; ++u) {
    const int n = ncol + u * 16;
    const float bv = bias1[n];
#pragma unroll
    for (int t = 0; t < 8; ++t) {
#pragma unroll
      for (int r = 0; r < 4; ++r) {
        const int m = mrow + t * 16 + r;
        if (m < M_TOT) {
          float v = acc[t][u][r] + bv;
          v = v > 0.f ? v : 0.f;
          h[(size_t)m * H_DIM + n] = f2bf(v);
        }
      }
    }
  }
}

// ---------------- GEMM2: y = h @ w2 + b2, same 2-barrier structure ---------
__global__ __launch_bounds__(512, 2) void gemm2_kernel(
    const unsigned short* __restrict__ hmat,
    const unsigned short* __restrict__ w2t,   // [512][2048]
    const float* __restrict__ bias2,
    float* __restrict__ out)
{
  __shared__ alignas(16) unsigned short lsA[32768];
  __shared__ alignas(16) unsigned short lsB[32768];

  const int tid  = threadIdx.x;
  const int lane = tid & 63;
  const int wave = tid >> 6;
  const int id = blockIdx.x;
  const int nt = id & 1;               // 2 col tiles of 256 (N=512)
  const int mt = id >> 1;

  const int m16 = tid & 15;
  const int g   = (tid >> 4) & 3;
  const int T0  = tid >> 6;

  int rowA0 = mt * 256 + T0 * 16 + m16;
  int rowA1 = rowA0 + 128;
  if (rowA0 >= M_TOT) rowA0 = M_TOT - 1;
  if (rowA1 >= M_TOT) rowA1 = M_TOT - 1;
  const unsigned short* pA0 = hmat + (size_t)rowA0 * H_DIM + g * 8;
  const unsigned short* pA1 = hmat + (size_t)rowA1 * H_DIM + g * 8;

  const int colB0 = nt * 256 + T0 * 16 + m16;
  const unsigned short* pB0 = w2t + (size_t)colB0 * H_DIM + g * 8;
  const unsigned short* pB1 = pB0 + (size_t)128 * H_DIM;

  const int wm = wave >> 2;
  const int wn = wave & 3;
  const int aBase = wm * 512 + lane;
  const int bBase = wn * 256 + lane;

  f32x4 acc[8][4] = {};

  const int KT = H_DIM / 64;           // 32 K-tiles

#define STAGE_A(TT, ks) { \
    unsigned short* d_ = lsA + ((TT) & 1) * 16384 + (ks) * 8192 + tid * 8; \
    const int ko_ = (TT) * 64 + (ks) * 32; \
    async16(pA0 + ko_, d_); async16(pA1 + ko_, d_ + 4096); }
#define STAGE_B(TT, ks) { \
    unsigned short* d_ = lsB + ((TT) & 1) * 16384 + (ks) * 8192 + tid * 8; \
    const int ko_ = (TT) * 64 + (ks) * 32; \
    async16(pB0 + ko_, d_); async16(pB1 + ko_, d_ + 4096); }

  STAGE_A(0, 0); STAGE_B(0, 0); STAGE_A(0, 1); STAGE_B(0, 1);
  STAGE_A(1, 0); STAGE_B(1, 0);
  VM4; SBAR; SCHED0;
  STAGE_A(1, 1); STAGE_B(1, 1);

  for (int kt = 0; kt < KT; ++kt) {
    const bf16x8* lA = (const bf16x8*)(lsA + (kt & 1) * 16384);
    const bf16x8* lB = (const bf16x8*)(lsB + (kt & 1) * 16384);
    bf16x8 a0, a1, a2, a3, a4, a5, a6, a7, b0, b1, b2, b3;

    // ---- region 1: ks0 ----
    LOAD_KS(0);
    PRIO1;
    MFMA32;
    PRIO0;
    SBAR; SCHED0;
    if (kt + 2 < KT) { STAGE_A(kt + 2, 0); STAGE_B(kt + 2, 0); }

    // ---- region 2: ks1 ----
    LOAD_KS(1024);
    PRIO1;
    MFMA32;
    PRIO0;
    SCHED0;
    if (kt >= KT - 2) { VM0; } else { VM4; }
    SBAR; SCHED0;
    if (kt + 2 < KT) { STAGE_A(kt + 2, 1); STAGE_B(kt + 2, 1); }
  }
#undef STAGE_A
#undef STAGE_B

  const int ncol = nt * 256 + wn * 64 + (lane & 15);
  const int mrow = mt * 256 + wm * 128 + (lane >> 4) * 4;
#pragma unroll
  for (int u = 0; u < 4; ++u) {
    const int n = ncol + u * 16;
    const float bv = bias2[n];
#pragma unroll
    for (int t = 0; t < 8; ++t) {
#pragma unroll
      for (int r = 0; r < 4; ++r) {
        const int m = mrow + t * 16 + r;
        if (m < M_TOT) {
          const int b = m / L_DIM;
          const int l = m - b * L_DIM;
          out[(size_t)b * SXF + (size_t)l * F_DIM + n] = acc[t][u][r] + bv;
        }
      }
    }
  }
}

// ---------------- conversion / transpose / pad helpers ----------------------
__global__ void cvt_bf16_kernel(const float* __restrict__ in,
                                unsigned short* __restrict__ out, int n4) {
  int idx = blockIdx.x * 256 + threadIdx.x;
  if (idx < n4) {
    float4 v = ((const float4*)in)[idx];
    ushort4 o;
    o.x = f2bf(v.x); o.y = f2bf(v.y); o.z = f2bf(v.z); o.w = f2bf(v.w);
    ((ushort4*)out)[idx] = o;
  }
}

// out[c][r] = bf16(in[r][c]); R, C multiples of 64
__global__ void transpose_cvt_kernel(const float* __restrict__ in,
                                     unsigned short* __restrict__ out, int R, int C) {
  __shared__ unsigned short tile[64][72];
  const int tx = threadIdx.x & 15;
  const int ty = threadIdx.x >> 4;
  const int r0 = blockIdx.x * 64;
  const int c0 = blockIdx.y * 64;
#pragma unroll
  for (int i = 0; i < 4; ++i) {
    const int r = r0 + ty + i * 16;
    float4 v = *(const float4*)(in + (size_t)r * C + c0 + tx * 4);
    tile[ty + i * 16][tx * 4 + 0] = f2bf(v.x);
    tile[ty + i * 16][tx * 4 + 1] = f2bf(v.y);
    tile[ty + i * 16][tx * 4 + 2] = f2bf(v.z);
    tile[ty + i * 16][tx * 4 + 3] = f2bf(v.w);
  }
  __syncthreads();
#pragma unroll
  for (int i = 0; i < 4; ++i) {
    const int c = c0 + ty + i * 16;
    ushort4 o;
    o.x = tile[tx * 4 + 0][ty + i * 16];
    o.y = tile[tx * 4 + 1][ty + i * 16];
    o.z = tile[tx * 4 + 2][ty + i * 16];
    o.w = tile[tx * 4 + 3][ty + i * 16];
    *(ushort4*)(out + (size_t)c * R + r0 + tx * 4) = o;
  }
}

__global__ void zero_pad_kernel(float* __restrict__ out) {
  int idx = blockIdx.x * 256 + threadIdx.x;          // 8 * 15 * 128 float4s
  if (idx < B_DIM * 15 * 128) {
    int b = idx / (15 * 128);
    int rem = idx - b * (15 * 128);
    int l = L_DIM + rem / 128;
    int f4 = rem - (rem / 128) * 128;
    ((float4*)out)[(size_t)b * (SXF / 4) + (size_t)l * 128 + f4] =
        make_float4(0.f, 0.f, 0.f, 0.f);
  }
}

__global__ void fill_sentinel(float* out, int n) {   // distinctive ws-too-small marker
  int idx = blockIdx.x * 256 + threadIdx.x;
  if (idx < n) out[idx] = 12345.0f;
}

extern "C" void kernel_launch(void* const* d_in, const int* in_sizes, int n_in,
                              void* d_out, int out_size, void* d_ws, size_t ws_size,
                              hipStream_t stream) {
  const float* x  = (const float*)d_in[0];
  const float* w1 = (const float*)d_in[1];
  const float* b1 = (const float*)d_in[2];
  const float* w2 = (const float*)d_in[3];
  const float* b2 = (const float*)d_in[4];
  float* out = (float*)d_out;

  const size_t OFF_H   = 0;                               // 32648*2048*2 = 133726208
  const size_t OFF_XB  = 133726208;                       // 16777216*2   = 33554432
  const size_t OFF_W1T = OFF_XB + 33554432;               // 8192*2048*2  = 33554432
  const size_t OFF_W2T = OFF_W1T + 33554432;              // 2048*512*2   = 2097152
  const size_t WS_NEED = OFF_W2T + 2097152;               // ~202.9 MB

  if (ws_size < WS_NEED) {
    fill_sentinel<<<65536, 256, 0, stream>>>(out, out_size);
    return;
  }

  unsigned short* hbuf = (unsigned short*)((char*)d_ws + OFF_H);
  unsigned short* xb   = (unsigned short*)((char*)d_ws + OFF_XB);
  unsigned short* w1t  = (unsigned short*)((char*)d_ws + OFF_W1T);
  unsigned short* w2t  = (unsigned short*)((char*)d_ws + OFF_W2T);

  cvt_bf16_kernel<<<16384, 256, 0, stream>>>(x, xb, 4194304);
  transpose_cvt_kernel<<<dim3(128, 32), 256, 0, stream>>>(w1, w1t, 8192, 2048);
  transpose_cvt_kernel<<<dim3(32, 8), 256, 0, stream>>>(w2, w2t, 2048, 512);
  gemm1_kernel<<<1024, 512, 0, stream>>>(xb, w1t, b1, hbuf);
  gemm2_kernel<<<256, 512, 0, stream>>>(hbuf, w2t, b2, out);
  zero_pad_kernel<<<60, 256, 0, stream>>>(out);
}

// Round 3
// 1171.120 us; speedup vs baseline: 1.7117x; 1.3475x over previous
//
#include <hip/hip_runtime.h>
#include <stdint.h>

#define B_DIM 8
#define S_DIM 4096
#define F_DIM 512
#define H_DIM 2048
#define W_DIM 16
#define L_DIM 4081               // S - W + 1
#define M_TOT 32648              // B * L
#define K1_DIM 8192              // W * F
#define SXF 2097152              // S * F

typedef __bf16 bf16x8 __attribute__((ext_vector_type(8)));
typedef float f32x4 __attribute__((ext_vector_type(4)));

__device__ __forceinline__ unsigned short f2bf(float f) {
  union { float f; uint32_t u; } a; a.f = f;
  return (unsigned short)((a.u + 0x7fffu + ((a.u >> 16) & 1u)) >> 16);
}

__device__ __forceinline__ void async16(const void* g, void* l) {
  __builtin_amdgcn_global_load_lds(
      (__attribute__((address_space(1))) void*)(uintptr_t)g,
      (__attribute__((address_space(3))) void*)l, 16, 0, 0);
}

#define SBAR   __builtin_amdgcn_s_barrier()
#define SCHED0 __builtin_amdgcn_sched_barrier(0)
#define PRIO1  __builtin_amdgcn_s_setprio(1)
#define PRIO0  __builtin_amdgcn_s_setprio(0)
#define VM0    asm volatile("s_waitcnt vmcnt(0)" ::: "memory")

// one accumulator row: acc[T][0..3] += AR x b0..b3
#define MROW(T, AR) \
  acc[T][0] = __builtin_amdgcn_mfma_f32_16x16x32_bf16(AR, b0, acc[T][0], 0, 0, 0); \
  acc[T][1] = __builtin_amdgcn_mfma_f32_16x16x32_bf16(AR, b1, acc[T][1], 0, 0, 0); \
  acc[T][2] = __builtin_amdgcn_mfma_f32_16x16x32_bf16(AR, b2, acc[T][2], 0, 0, 0); \
  acc[T][3] = __builtin_amdgcn_mfma_f32_16x16x32_bf16(AR, b3, acc[T][3], 0, 0, 0);

#define MFMA32 \
  MROW(0, a0) MROW(1, a1) MROW(2, a2) MROW(3, a3) \
  MROW(4, a4) MROW(5, a5) MROW(6, a6) MROW(7, a7)

// reads from swizzled row-major LDS: A rows stride 128 B, frag rt stride 2048 B
#define LOAD_KS(AO, BO) \
  a0 = *(const bf16x8*)(p + (AO));          a1 = *(const bf16x8*)(p + (AO) + 2048); \
  a2 = *(const bf16x8*)(p + (AO) + 4096);   a3 = *(const bf16x8*)(p + (AO) + 6144); \
  a4 = *(const bf16x8*)(p + (AO) + 8192);   a5 = *(const bf16x8*)(p + (AO) + 10240); \
  a6 = *(const bf16x8*)(p + (AO) + 12288);  a7 = *(const bf16x8*)(p + (AO) + 14336); \
  b0 = *(const bf16x8*)(p + (BO));          b1 = *(const bf16x8*)(p + (BO) + 2048); \
  b2 = *(const bf16x8*)(p + (BO) + 4096);   b3 = *(const bf16x8*)(p + (BO) + 6144);

// ---------------- GEMM1: h = relu(x_hankel @ w1 + b1) ----------------------
// 256x256 tile, BK=64, 8 waves (2M x 4N, each 128x64).
// LDS: 2 full buffers x (A 32KB + B 32KB) = 128 KB. Row-major [256][64]bf16
// tiles with T2 XOR swizzle: 16B slot p of row r holds column-group
// c8 = p ^ (r&7). Staging wave covers 8 rows x 128 B CONTIGUOUS per row
// (vs 16 rows x 64 B of the old fragment-order layout -> half the memory
// transactions; this was the shared 33%-MfmaUtil ceiling of r1/r2).
// Global source is pre-swizzled per-lane (m173): linear LDS dest, swizzled
// read addresses (8 lanes/bank-group = conflict-free b128).
// Schedule: 1 sync/K-tile. During tile kt: read+MFMA buf[kt&1], stage tile
// kt+1 into buf[(kt+1)&1] (disjoint -> no mid-tile barrier); end of tile:
// vmcnt(0)+s_barrier (stages had ~full tile of latency cover).
__global__ __launch_bounds__(512, 2) void gemm1_kernel(
    const unsigned short* __restrict__ xb,
    const unsigned short* __restrict__ w1t,
    const float* __restrict__ bias1,
    unsigned short* __restrict__ h)
{
  __shared__ alignas(16) unsigned char lsm[131072];  // [2][A 32K | B 32K]

  const int tid  = threadIdx.x;
  const int lane = tid & 63;
  const int wave = tid >> 6;           // 0..7
  const int id = blockIdx.x;
  const int nt = id & 7;               // XCD-pinned B column
  const int mt = id >> 3;

  // ---- staging decode: thread t covers row rr(+s*64), 16B slot (t&7),
  //      swizzled global col-group ((t&7) ^ (rr&7)) ----
  const int rr   = tid >> 3;           // 0..63
  const int xoro = (((tid & 7) ^ (rr & 7)) << 3);  // element offset in row

  const unsigned short* pA0; const unsigned short* pA1;
  const unsigned short* pA2; const unsigned short* pA3;
#define MKPA(PS, S) { \
    int m = mt * 256 + (S) * 64 + rr; \
    if (m >= M_TOT) m = M_TOT - 1; \
    const int b_ = m / L_DIM, l_ = m - b_ * L_DIM; \
    PS = xb + (size_t)b_ * SXF + (size_t)l_ * F_DIM + xoro; }
  MKPA(pA0, 0) MKPA(pA1, 1) MKPA(pA2, 2) MKPA(pA3, 3)
#undef MKPA
  const unsigned short* pB0 = w1t + (size_t)(nt * 256 +   0 + rr) * K1_DIM + xoro;
  const unsigned short* pB1 = w1t + (size_t)(nt * 256 +  64 + rr) * K1_DIM + xoro;
  const unsigned short* pB2 = w1t + (size_t)(nt * 256 + 128 + rr) * K1_DIM + xoro;
  const unsigned short* pB3 = w1t + (size_t)(nt * 256 + 192 + rr) * K1_DIM + xoro;

  const int wm = wave >> 2;            // 0..1 : 128-row band
  const int wn = wave & 3;             // 0..3 : 64-col band

  // ---- consumer lane bases (swizzled): row = band + (lane&15),
  //      slot = (ks*4 + lane>>4) ^ (lane&7); ks1 = ks0 ^ 64 bytes ----
  const int l15 = lane & 15;
  const int slot0 = ((lane >> 4) ^ (lane & 7)) << 4;
  const int aoff  = (wm * 128 + l15) * 128 + slot0;            // A at +0
  const int aoff1 = aoff ^ 64;
  const int boff  = 32768 + (wn * 64 + l15) * 128 + slot0;     // B at +32K
  const int boff1 = boff ^ 64;

  f32x4 acc[8][4] = {};

  const int KT = K1_DIM / 64;          // 128 K-tiles

#define STAGE_A(TT) { \
    const size_t ko_ = (size_t)(TT) * 64; \
    unsigned char* d_ = lsm + (((TT) & 1) << 16) + tid * 16; \
    async16(pA0 + ko_, d_);         async16(pA1 + ko_, d_ + 8192); \
    async16(pA2 + ko_, d_ + 16384); async16(pA3 + ko_, d_ + 24576); }
#define STAGE_B(TT) { \
    const size_t ko_ = (size_t)(TT) * 64; \
    unsigned char* d_ = lsm + (((TT) & 1) << 16) + 32768 + tid * 16; \
    async16(pB0 + ko_, d_);         async16(pB1 + ko_, d_ + 8192); \
    async16(pB2 + ko_, d_ + 16384); async16(pB3 + ko_, d_ + 24576); }

  // prologue: stage tile 0, wait, go
  STAGE_A(0); STAGE_B(0);
  VM0; SBAR; SCHED0;

  for (int kt = 0; kt < KT; ++kt) {
    const unsigned char* p = lsm + ((kt & 1) << 16);
    bf16x8 a0, a1, a2, a3, a4, a5, a6, a7, b0, b1, b2, b3;

    LOAD_KS(aoff, boff);                       // ks0 frags
    if (kt + 1 < KT) STAGE_A(kt + 1);          // early-issue next-tile A
    PRIO1; MFMA32; PRIO0;

    LOAD_KS(aoff1, boff1);                     // ks1 frags
    if (kt + 1 < KT) STAGE_B(kt + 1);          // next-tile B
    PRIO1; MFMA32; PRIO0;

    VM0; SBAR; SCHED0;                         // next tile landed; buffers flip
  }
#undef STAGE_A
#undef STAGE_B

  // C/D layout: col = lane&15, row = (lane>>4)*4 + reg
  const int ncol = nt * 256 + wn * 64 + l15;
  const int mrow = mt * 256 + wm * 128 + (lane >> 4) * 4;
#pragma unroll
  for (int u = 0; u < 4; ++u) {
    const int n = ncol + u * 16;
    const float bv = bias1[n];
#pragma unroll
    for (int t = 0; t < 8; ++t) {
#pragma unroll
      for (int r = 0; r < 4; ++r) {
        const int m = mrow + t * 16 + r;
        if (m < M_TOT) {
          float v = acc[t][u][r] + bv;
          v = v > 0.f ? v : 0.f;
          h[(size_t)m * H_DIM + n] = f2bf(v);
        }
      }
    }
  }
}

// ---------------- GEMM2: y = h @ w2 + b2, same structure, KT=32 ------------
__global__ __launch_bounds__(512, 2) void gemm2_kernel(
    const unsigned short* __restrict__ hmat,
    const unsigned short* __restrict__ w2t,   // [512][2048]
    const float* __restrict__ bias2,
    float* __restrict__ out)
{
  __shared__ alignas(16) unsigned char lsm[131072];

  const int tid  = threadIdx.x;
  const int lane = tid & 63;
  const int wave = tid >> 6;
  const int id = blockIdx.x;
  const int nt = id & 1;               // 2 col tiles of 256 (N=512)
  const int mt = id >> 1;

  const int rr   = tid >> 3;
  const int xoro = (((tid & 7) ^ (rr & 7)) << 3);

  const unsigned short* pA0; const unsigned short* pA1;
  const unsigned short* pA2; const unsigned short* pA3;
#define MKPA(PS, S) { \
    int m = mt * 256 + (S) * 64 + rr; \
    if (m >= M_TOT) m = M_TOT - 1; \
    PS = hmat + (size_t)m * H_DIM + xoro; }
  MKPA(pA0, 0) MKPA(pA1, 1) MKPA(pA2, 2) MKPA(pA3, 3)
#undef MKPA
  const unsigned short* pB0 = w2t + (size_t)(nt * 256 +   0 + rr) * H_DIM + xoro;
  const unsigned short* pB1 = w2t + (size_t)(nt * 256 +  64 + rr) * H_DIM + xoro;
  const unsigned short* pB2 = w2t + (size_t)(nt * 256 + 128 + rr) * H_DIM + xoro;
  const unsigned short* pB3 = w2t + (size_t)(nt * 256 + 192 + rr) * H_DIM + xoro;

  const int wm = wave >> 2;
  const int wn = wave & 3;
  const int l15 = lane & 15;
  const int slot0 = ((lane >> 4) ^ (lane & 7)) << 4;
  const int aoff  = (wm * 128 + l15) * 128 + slot0;
  const int aoff1 = aoff ^ 64;
  const int boff  = 32768 + (wn * 64 + l15) * 128 + slot0;
  const int boff1 = boff ^ 64;

  f32x4 acc[8][4] = {};

  const int KT = H_DIM / 64;           // 32 K-tiles

#define STAGE_A(TT) { \
    const size_t ko_ = (size_t)(TT) * 64; \
    unsigned char* d_ = lsm + (((TT) & 1) << 16) + tid * 16; \
    async16(pA0 + ko_, d_);         async16(pA1 + ko_, d_ + 8192); \
    async16(pA2 + ko_, d_ + 16384); async16(pA3 + ko_, d_ + 24576); }
#define STAGE_B(TT) { \
    const size_t ko_ = (size_t)(TT) * 64; \
    unsigned char* d_ = lsm + (((TT) & 1) << 16) + 32768 + tid * 16; \
    async16(pB0 + ko_, d_);         async16(pB1 + ko_, d_ + 8192); \
    async16(pB2 + ko_, d_ + 16384); async16(pB3 + ko_, d_ + 24576); }

  STAGE_A(0); STAGE_B(0);
  VM0; SBAR; SCHED0;

  for (int kt = 0; kt < KT; ++kt) {
    const unsigned char* p = lsm + ((kt & 1) << 16);
    bf16x8 a0, a1, a2, a3, a4, a5, a6, a7, b0, b1, b2, b3;

    LOAD_KS(aoff, boff);
    if (kt + 1 < KT) STAGE_A(kt + 1);
    PRIO1; MFMA32; PRIO0;

    LOAD_KS(aoff1, boff1);
    if (kt + 1 < KT) STAGE_B(kt + 1);
    PRIO1; MFMA32; PRIO0;

    VM0; SBAR; SCHED0;
  }
#undef STAGE_A
#undef STAGE_B

  const int ncol = nt * 256 + wn * 64 + l15;
  const int mrow = mt * 256 + wm * 128 + (lane >> 4) * 4;
#pragma unroll
  for (int u = 0; u < 4; ++u) {
    const int n = ncol + u * 16;
    const float bv = bias2[n];
#pragma unroll
    for (int t = 0; t < 8; ++t) {
#pragma unroll
      for (int r = 0; r < 4; ++r) {
        const int m = mrow + t * 16 + r;
        if (m < M_TOT) {
          const int b = m / L_DIM;
          const int l = m - b * L_DIM;
          out[(size_t)b * SXF + (size_t)l * F_DIM + n] = acc[t][u][r] + bv;
        }
      }
    }
  }
}

// ---------------- conversion / transpose / pad helpers ----------------------
__global__ void cvt_bf16_kernel(const float* __restrict__ in,
                                unsigned short* __restrict__ out, int n4) {
  int idx = blockIdx.x * 256 + threadIdx.x;
  if (idx < n4) {
    float4 v = ((const float4*)in)[idx];
    ushort4 o;
    o.x = f2bf(v.x); o.y = f2bf(v.y); o.z = f2bf(v.z); o.w = f2bf(v.w);
    ((ushort4*)out)[idx] = o;
  }
}

// out[c][r] = bf16(in[r][c]); R, C multiples of 64
__global__ void transpose_cvt_kernel(const float* __restrict__ in,
                                     unsigned short* __restrict__ out, int R, int C) {
  __shared__ unsigned short tile[64][72];
  const int tx = threadIdx.x & 15;
  const int ty = threadIdx.x >> 4;
  const int r0 = blockIdx.x * 64;
  const int c0 = blockIdx.y * 64;
#pragma unroll
  for (int i = 0; i < 4; ++i) {
    const int r = r0 + ty + i * 16;
    float4 v = *(const float4*)(in + (size_t)r * C + c0 + tx * 4);
    tile[ty + i * 16][tx * 4 + 0] = f2bf(v.x);
    tile[ty + i * 16][tx * 4 + 1] = f2bf(v.y);
    tile[ty + i * 16][tx * 4 + 2] = f2bf(v.z);
    tile[ty + i * 16][tx * 4 + 3] = f2bf(v.w);
  }
  __syncthreads();
#pragma unroll
  for (int i = 0; i < 4; ++i) {
    const int c = c0 + ty + i * 16;
    ushort4 o;
    o.x = tile[tx * 4 + 0][ty + i * 16];
    o.y = tile[tx * 4 + 1][ty + i * 16];
    o.z = tile[tx * 4 + 2][ty + i * 16];
    o.w = tile[tx * 4 + 3][ty + i * 16];
    *(ushort4*)(out + (size_t)c * R + r0 + tx * 4) = o;
  }
}

__global__ void zero_pad_kernel(float* __restrict__ out) {
  int idx = blockIdx.x * 256 + threadIdx.x;          // 8 * 15 * 128 float4s
  if (idx < B_DIM * 15 * 128) {
    int b = idx / (15 * 128);
    int rem = idx - b * (15 * 128);
    int l = L_DIM + rem / 128;
    int f4 = rem - (rem / 128) * 128;
    ((float4*)out)[(size_t)b * (SXF / 4) + (size_t)l * 128 + f4] =
        make_float4(0.f, 0.f, 0.f, 0.f);
  }
}

__global__ void fill_sentinel(float* out, int n) {   // distinctive ws-too-small marker
  int idx = blockIdx.x * 256 + threadIdx.x;
  if (idx < n) out[idx] = 12345.0f;
}

extern "C" void kernel_launch(void* const* d_in, const int* in_sizes, int n_in,
                              void* d_out, int out_size, void* d_ws, size_t ws_size,
                              hipStream_t stream) {
  const float* x  = (const float*)d_in[0];
  const float* w1 = (const float*)d_in[1];
  const float* b1 = (const float*)d_in[2];
  const float* w2 = (const float*)d_in[3];
  const float* b2 = (const float*)d_in[4];
  float* out = (float*)d_out;

  const size_t OFF_H   = 0;                               // 32648*2048*2 = 133726208
  const size_t OFF_XB  = 133726208;                       // 16777216*2   = 33554432
  const size_t OFF_W1T = OFF_XB + 33554432;               // 8192*2048*2  = 33554432
  const size_t OFF_W2T = OFF_W1T + 33554432;              // 2048*512*2   = 2097152
  const size_t WS_NEED = OFF_W2T + 2097152;               // ~202.9 MB

  if (ws_size < WS_NEED) {
    fill_sentinel<<<65536, 256, 0, stream>>>(out, out_size);
    return;
  }

  unsigned short* hbuf = (unsigned short*)((char*)d_ws + OFF_H);
  unsigned short* xb   = (unsigned short*)((char*)d_ws + OFF_XB);
  unsigned short* w1t  = (unsigned short*)((char*)d_ws + OFF_W1T);
  unsigned short* w2t  = (unsigned short*)((char*)d_ws + OFF_W2T);

  cvt_bf16_kernel<<<16384, 256, 0, stream>>>(x, xb, 4194304);
  transpose_cvt_kernel<<<dim3(128, 32), 256, 0, stream>>>(w1, w1t, 8192, 2048);
  transpose_cvt_kernel<<<dim3(32, 8), 256, 0, stream>>>(w2, w2t, 2048, 512);
  gemm1_kernel<<<1024, 512, 0, stream>>>(xb, w1t, b1, hbuf);
  gemm2_kernel<<<256, 512, 0, stream>>>(hbuf, w2t, b2, out);
  zero_pad_kernel<<<60, 256, 0, stream>>>(out);
}

// Round 4
// 1149.920 us; speedup vs baseline: 1.7433x; 1.0184x over previous
//
#include <hip/hip_runtime.h>
#include <stdint.h>

#define B_DIM 8
#define S_DIM 4096
#define F_DIM 512
#define H_DIM 2048
#define W_DIM 16
#define L_DIM 4081               // S - W + 1
#define M_TOT 32648              // B * L
#define K1_DIM 8192              // W * F
#define SXF 2097152              // S * F

typedef __bf16 bf16x8 __attribute__((ext_vector_type(8)));
typedef float f32x4 __attribute__((ext_vector_type(4)));

__device__ __forceinline__ unsigned short f2bf(float f) {
  union { float f; uint32_t u; } a; a.f = f;
  return (unsigned short)((a.u + 0x7fffu + ((a.u >> 16) & 1u)) >> 16);
}

__device__ __forceinline__ void async16(const void* g, void* l) {
  __builtin_amdgcn_global_load_lds(
      (__attribute__((address_space(1))) void*)(uintptr_t)g,
      (__attribute__((address_space(3))) void*)l, 16, 0, 0);
}

#define SBAR   __builtin_amdgcn_s_barrier()
#define SCHED0 __builtin_amdgcn_sched_barrier(0)
#define PRIO1  __builtin_amdgcn_s_setprio(1)
#define PRIO0  __builtin_amdgcn_s_setprio(0)
#define VM0    asm volatile("s_waitcnt vmcnt(0)" ::: "memory")

// one accumulator row: acc[T][0..3] += AR x b0..b3
#define MROW(T, AR) \
  acc[T][0] = __builtin_amdgcn_mfma_f32_16x16x32_bf16(AR, b0, acc[T][0], 0, 0, 0); \
  acc[T][1] = __builtin_amdgcn_mfma_f32_16x16x32_bf16(AR, b1, acc[T][1], 0, 0, 0); \
  acc[T][2] = __builtin_amdgcn_mfma_f32_16x16x32_bf16(AR, b2, acc[T][2], 0, 0, 0); \
  acc[T][3] = __builtin_amdgcn_mfma_f32_16x16x32_bf16(AR, b3, acc[T][3], 0, 0, 0);

#define MFMA32 \
  MROW(0, a0) MROW(1, a1) MROW(2, a2) MROW(3, a3) \
  MROW(4, a4) MROW(5, a5) MROW(6, a6) MROW(7, a7)

// reads from swizzled row-major LDS: A rows stride 128 B, frag rt stride 2048 B
#define LOAD_KS(AO, BO) \
  a0 = *(const bf16x8*)(p + (AO));          a1 = *(const bf16x8*)(p + (AO) + 2048); \
  a2 = *(const bf16x8*)(p + (AO) + 4096);   a3 = *(const bf16x8*)(p + (AO) + 6144); \
  a4 = *(const bf16x8*)(p + (AO) + 8192);   a5 = *(const bf16x8*)(p + (AO) + 10240); \
  a6 = *(const bf16x8*)(p + (AO) + 12288);  a7 = *(const bf16x8*)(p + (AO) + 14336); \
  b0 = *(const bf16x8*)(p + (BO));          b1 = *(const bf16x8*)(p + (BO) + 2048); \
  b2 = *(const bf16x8*)(p + (BO) + 4096);   b3 = *(const bf16x8*)(p + (BO) + 6144);

// ---------------- GEMM1: h = relu(x_hankel @ w1 + b1) ----------------------
// 256x256 tile, BK=64, 8 waves (2M x 4N, each 128x64). Round-3 structure
// (row-major swizzled LDS, 128 B staging granule, 1 vmcnt(0)+s_barrier per
// K-tile) with ONE change: both next-tile stages (B first - it was the
// late one) issue at the TOP of the tile body, before any ds_read. This
// gives the last-issued stage a full ~4600 cy of MFMA cover before the
// end-of-tile drain (r3 gave B only ~2300 cy: measured ~1700 cy/tile
// drain stall = the gap between 50% MfmaUtil and the ~85% overlap
// ceiling). Register-limited to 1 block/CU, so the drain cannot be hidden
// by another block - it must be covered within the tile.
__global__ __launch_bounds__(512, 2) void gemm1_kernel(
    const unsigned short* __restrict__ xb,
    const unsigned short* __restrict__ w1t,
    const float* __restrict__ bias1,
    unsigned short* __restrict__ h)
{
  __shared__ alignas(16) unsigned char lsm[131072];  // [2][A 32K | B 32K]

  const int tid  = threadIdx.x;
  const int lane = tid & 63;
  const int wave = tid >> 6;           // 0..7
  const int id = blockIdx.x;
  const int nt = id & 7;               // XCD-pinned B column
  const int mt = id >> 3;

  // ---- staging decode: thread t covers row rr(+s*64), 16B slot (t&7),
  //      swizzled global col-group ((t&7) ^ (rr&7)) ----
  const int rr   = tid >> 3;           // 0..63
  const int xoro = (((tid & 7) ^ (rr & 7)) << 3);  // element offset in row

  const unsigned short* pA0; const unsigned short* pA1;
  const unsigned short* pA2; const unsigned short* pA3;
#define MKPA(PS, S) { \
    int m = mt * 256 + (S) * 64 + rr; \
    if (m >= M_TOT) m = M_TOT - 1; \
    const int b_ = m / L_DIM, l_ = m - b_ * L_DIM; \
    PS = xb + (size_t)b_ * SXF + (size_t)l_ * F_DIM + xoro; }
  MKPA(pA0, 0) MKPA(pA1, 1) MKPA(pA2, 2) MKPA(pA3, 3)
#undef MKPA
  const unsigned short* pB0 = w1t + (size_t)(nt * 256 +   0 + rr) * K1_DIM + xoro;
  const unsigned short* pB1 = w1t + (size_t)(nt * 256 +  64 + rr) * K1_DIM + xoro;
  const unsigned short* pB2 = w1t + (size_t)(nt * 256 + 128 + rr) * K1_DIM + xoro;
  const unsigned short* pB3 = w1t + (size_t)(nt * 256 + 192 + rr) * K1_DIM + xoro;

  const int wm = wave >> 2;            // 0..1 : 128-row band
  const int wn = wave & 3;             // 0..3 : 64-col band

  // ---- consumer lane bases (swizzled): row = band + (lane&15),
  //      slot = (ks*4 + lane>>4) ^ (lane&7); ks1 = ks0 ^ 64 bytes ----
  const int l15 = lane & 15;
  const int slot0 = ((lane >> 4) ^ (lane & 7)) << 4;
  const int aoff  = (wm * 128 + l15) * 128 + slot0;            // A at +0
  const int aoff1 = aoff ^ 64;
  const int boff  = 32768 + (wn * 64 + l15) * 128 + slot0;     // B at +32K
  const int boff1 = boff ^ 64;

  f32x4 acc[8][4] = {};

  const int KT = K1_DIM / 64;          // 128 K-tiles

#define STAGE_A(TT) { \
    const size_t ko_ = (size_t)(TT) * 64; \
    unsigned char* d_ = lsm + (((TT) & 1) << 16) + tid * 16; \
    async16(pA0 + ko_, d_);         async16(pA1 + ko_, d_ + 8192); \
    async16(pA2 + ko_, d_ + 16384); async16(pA3 + ko_, d_ + 24576); }
#define STAGE_B(TT) { \
    const size_t ko_ = (size_t)(TT) * 64; \
    unsigned char* d_ = lsm + (((TT) & 1) << 16) + 32768 + tid * 16; \
    async16(pB0 + ko_, d_);         async16(pB1 + ko_, d_ + 8192); \
    async16(pB2 + ko_, d_ + 16384); async16(pB3 + ko_, d_ + 24576); }

  // prologue: stage tile 0, wait, go
  STAGE_B(0); STAGE_A(0);
  VM0; SBAR; SCHED0;

  for (int kt = 0; kt < KT; ++kt) {
    const unsigned char* p = lsm + ((kt & 1) << 16);
    bf16x8 a0, a1, a2, a3, a4, a5, a6, a7, b0, b1, b2, b3;

    // issue ALL next-tile stages first: max latency cover before the drain
    if (kt + 1 < KT) { STAGE_B(kt + 1); STAGE_A(kt + 1); }

    LOAD_KS(aoff, boff);                       // ks0 frags
    PRIO1; MFMA32; PRIO0;

    LOAD_KS(aoff1, boff1);                     // ks1 frags
    PRIO1; MFMA32; PRIO0;

    VM0; SBAR; SCHED0;                         // next tile landed; buffers flip
  }
#undef STAGE_A
#undef STAGE_B

  // C/D layout: col = lane&15, row = (lane>>4)*4 + reg
  const int ncol = nt * 256 + wn * 64 + l15;
  const int mrow = mt * 256 + wm * 128 + (lane >> 4) * 4;
#pragma unroll
  for (int u = 0; u < 4; ++u) {
    const int n = ncol + u * 16;
    const float bv = bias1[n];
#pragma unroll
    for (int t = 0; t < 8; ++t) {
#pragma unroll
      for (int r = 0; r < 4; ++r) {
        const int m = mrow + t * 16 + r;
        if (m < M_TOT) {
          float v = acc[t][u][r] + bv;
          v = v > 0.f ? v : 0.f;
          h[(size_t)m * H_DIM + n] = f2bf(v);
        }
      }
    }
  }
}

// ---------------- GEMM2: y = h @ w2 + b2, same structure, KT=32 ------------
__global__ __launch_bounds__(512, 2) void gemm2_kernel(
    const unsigned short* __restrict__ hmat,
    const unsigned short* __restrict__ w2t,   // [512][2048]
    const float* __restrict__ bias2,
    float* __restrict__ out)
{
  __shared__ alignas(16) unsigned char lsm[131072];

  const int tid  = threadIdx.x;
  const int lane = tid & 63;
  const int wave = tid >> 6;
  const int id = blockIdx.x;
  const int nt = id & 1;               // 2 col tiles of 256 (N=512)
  const int mt = id >> 1;

  const int rr   = tid >> 3;
  const int xoro = (((tid & 7) ^ (rr & 7)) << 3);

  const unsigned short* pA0; const unsigned short* pA1;
  const unsigned short* pA2; const unsigned short* pA3;
#define MKPA(PS, S) { \
    int m = mt * 256 + (S) * 64 + rr; \
    if (m >= M_TOT) m = M_TOT - 1; \
    PS = hmat + (size_t)m * H_DIM + xoro; }
  MKPA(pA0, 0) MKPA(pA1, 1) MKPA(pA2, 2) MKPA(pA3, 3)
#undef MKPA
  const unsigned short* pB0 = w2t + (size_t)(nt * 256 +   0 + rr) * H_DIM + xoro;
  const unsigned short* pB1 = w2t + (size_t)(nt * 256 +  64 + rr) * H_DIM + xoro;
  const unsigned short* pB2 = w2t + (size_t)(nt * 256 + 128 + rr) * H_DIM + xoro;
  const unsigned short* pB3 = w2t + (size_t)(nt * 256 + 192 + rr) * H_DIM + xoro;

  const int wm = wave >> 2;
  const int wn = wave & 3;
  const int l15 = lane & 15;
  const int slot0 = ((lane >> 4) ^ (lane & 7)) << 4;
  const int aoff  = (wm * 128 + l15) * 128 + slot0;
  const int aoff1 = aoff ^ 64;
  const int boff  = 32768 + (wn * 64 + l15) * 128 + slot0;
  const int boff1 = boff ^ 64;

  f32x4 acc[8][4] = {};

  const int KT = H_DIM / 64;           // 32 K-tiles

#define STAGE_A(TT) { \
    const size_t ko_ = (size_t)(TT) * 64; \
    unsigned char* d_ = lsm + (((TT) & 1) << 16) + tid * 16; \
    async16(pA0 + ko_, d_);         async16(pA1 + ko_, d_ + 8192); \
    async16(pA2 + ko_, d_ + 16384); async16(pA3 + ko_, d_ + 24576); }
#define STAGE_B(TT) { \
    const size_t ko_ = (size_t)(TT) * 64; \
    unsigned char* d_ = lsm + (((TT) & 1) << 16) + 32768 + tid * 16; \
    async16(pB0 + ko_, d_);         async16(pB1 + ko_, d_ + 8192); \
    async16(pB2 + ko_, d_ + 16384); async16(pB3 + ko_, d_ + 24576); }

  STAGE_B(0); STAGE_A(0);
  VM0; SBAR; SCHED0;

  for (int kt = 0; kt < KT; ++kt) {
    const unsigned char* p = lsm + ((kt & 1) << 16);
    bf16x8 a0, a1, a2, a3, a4, a5, a6, a7, b0, b1, b2, b3;

    if (kt + 1 < KT) { STAGE_B(kt + 1); STAGE_A(kt + 1); }

    LOAD_KS(aoff, boff);
    PRIO1; MFMA32; PRIO0;

    LOAD_KS(aoff1, boff1);
    PRIO1; MFMA32; PRIO0;

    VM0; SBAR; SCHED0;
  }
#undef STAGE_A
#undef STAGE_B

  const int ncol = nt * 256 + wn * 64 + l15;
  const int mrow = mt * 256 + wm * 128 + (lane >> 4) * 4;
#pragma unroll
  for (int u = 0; u < 4; ++u) {
    const int n = ncol + u * 16;
    const float bv = bias2[n];
#pragma unroll
    for (int t = 0; t < 8; ++t) {
#pragma unroll
      for (int r = 0; r < 4; ++r) {
        const int m = mrow + t * 16 + r;
        if (m < M_TOT) {
          const int b = m / L_DIM;
          const int l = m - b * L_DIM;
          out[(size_t)b * SXF + (size_t)l * F_DIM + n] = acc[t][u][r] + bv;
        }
      }
    }
  }
}

// ---------------- conversion / transpose / pad helpers ----------------------
__global__ void cvt_bf16_kernel(const float* __restrict__ in,
                                unsigned short* __restrict__ out, int n4) {
  int idx = blockIdx.x * 256 + threadIdx.x;
  if (idx < n4) {
    float4 v = ((const float4*)in)[idx];
    ushort4 o;
    o.x = f2bf(v.x); o.y = f2bf(v.y); o.z = f2bf(v.z); o.w = f2bf(v.w);
    ((ushort4*)out)[idx] = o;
  }
}

// out[c][r] = bf16(in[r][c]); R, C multiples of 64
__global__ void transpose_cvt_kernel(const float* __restrict__ in,
                                     unsigned short* __restrict__ out, int R, int C) {
  __shared__ unsigned short tile[64][72];
  const int tx = threadIdx.x & 15;
  const int ty = threadIdx.x >> 4;
  const int r0 = blockIdx.x * 64;
  const int c0 = blockIdx.y * 64;
#pragma unroll
  for (int i = 0; i < 4; ++i) {
    const int r = r0 + ty + i * 16;
    float4 v = *(const float4*)(in + (size_t)r * C + c0 + tx * 4);
    tile[ty + i * 16][tx * 4 + 0] = f2bf(v.x);
    tile[ty + i * 16][tx * 4 + 1] = f2bf(v.y);
    tile[ty + i * 16][tx * 4 + 2] = f2bf(v.z);
    tile[ty + i * 16][tx * 4 + 3] = f2bf(v.w);
  }
  __syncthreads();
#pragma unroll
  for (int i = 0; i < 4; ++i) {
    const int c = c0 + ty + i * 16;
    ushort4 o;
    o.x = tile[tx * 4 + 0][ty + i * 16];
    o.y = tile[tx * 4 + 1][ty + i * 16];
    o.z = tile[tx * 4 + 2][ty + i * 16];
    o.w = tile[tx * 4 + 3][ty + i * 16];
    *(ushort4*)(out + (size_t)c * R + r0 + tx * 4) = o;
  }
}

__global__ void zero_pad_kernel(float* __restrict__ out) {
  int idx = blockIdx.x * 256 + threadIdx.x;          // 8 * 15 * 128 float4s
  if (idx < B_DIM * 15 * 128) {
    int b = idx / (15 * 128);
    int rem = idx - b * (15 * 128);
    int l = L_DIM + rem / 128;
    int f4 = rem - (rem / 128) * 128;
    ((float4*)out)[(size_t)b * (SXF / 4) + (size_t)l * 128 + f4] =
        make_float4(0.f, 0.f, 0.f, 0.f);
  }
}

__global__ void fill_sentinel(float* out, int n) {   // distinctive ws-too-small marker
  int idx = blockIdx.x * 256 + threadIdx.x;
  if (idx < n) out[idx] = 12345.0f;
}

extern "C" void kernel_launch(void* const* d_in, const int* in_sizes, int n_in,
                              void* d_out, int out_size, void* d_ws, size_t ws_size,
                              hipStream_t stream) {
  const float* x  = (const float*)d_in[0];
  const float* w1 = (const float*)d_in[1];
  const float* b1 = (const float*)d_in[2];
  const float* w2 = (const float*)d_in[3];
  const float* b2 = (const float*)d_in[4];
  float* out = (float*)d_out;

  const size_t OFF_H   = 0;                               // 32648*2048*2 = 133726208
  const size_t OFF_XB  = 133726208;                       // 16777216*2   = 33554432
  const size_t OFF_W1T = OFF_XB + 33554432;               // 8192*2048*2  = 33554432
  const size_t OFF_W2T = OFF_W1T + 33554432;              // 2048*512*2   = 2097152
  const size_t WS_NEED = OFF_W2T + 2097152;               // ~202.9 MB

  if (ws_size < WS_NEED) {
    fill_sentinel<<<65536, 256, 0, stream>>>(out, out_size);
    return;
  }

  unsigned short* hbuf = (unsigned short*)((char*)d_ws + OFF_H);
  unsigned short* xb   = (unsigned short*)((char*)d_ws + OFF_XB);
  unsigned short* w1t  = (unsigned short*)((char*)d_ws + OFF_W1T);
  unsigned short* w2t  = (unsigned short*)((char*)d_ws + OFF_W2T);

  cvt_bf16_kernel<<<16384, 256, 0, stream>>>(x, xb, 4194304);
  transpose_cvt_kernel<<<dim3(128, 32), 256, 0, stream>>>(w1, w1t, 8192, 2048);
  transpose_cvt_kernel<<<dim3(32, 8), 256, 0, stream>>>(w2, w2t, 2048, 512);
  gemm1_kernel<<<1024, 512, 0, stream>>>(xb, w1t, b1, hbuf);
  gemm2_kernel<<<256, 512, 0, stream>>>(hbuf, w2t, b2, out);
  zero_pad_kernel<<<60, 256, 0, stream>>>(out);
}